// Round 2
// baseline (286.950 us; speedup 1.0000x reference)
//
#include <hip/hip_runtime.h>
#include <hip/hip_cooperative_groups.h>
#include <cstdint>
#include <cstddef>

namespace cg = cooperative_groups;

constexpr int CDIM   = 256;   // channels
constexpr int CR     = 64;    // reduced channels
constexpr int NROW   = 4096;  // tokens per batch
constexpr int NBATCH = 8;
constexpr int GRID   = 1024;            // 4 blocks/CU on 256 CUs (co-resident)
constexpr int BPB    = GRID / NBATCH;   // 128 blocks per batch
constexpr int RPB    = NROW / BPB;      // 32 rows per block
constexpr int RPW    = RPB / 4;         // 8 rows per wave

__global__ __launch_bounds__(256, 4) void k_fused(
    const float* __restrict__ x,  const float* __restrict__ lnw,
    const float* __restrict__ lnb, const float* __restrict__ pw,
    const float* __restrict__ pb,  float* __restrict__ S,
    unsigned long long* __restrict__ amax, float* __restrict__ out)
{
    cg::grid_group grid = cg::this_grid();
    const int blk  = blockIdx.x;
    const int t    = threadIdx.x;
    const int wave = t >> 6;
    const int lane = t & 63;

    __shared__ float lds[4][CDIM];
    __shared__ unsigned long long wbest[4];
    __shared__ float red[8];
    __shared__ float y[CDIM];

    // ---------------- phase 0: zero accumulators (atomic => XCD-coherent)
    if (blk < NBATCH)                     atomicExch(&S[blk * CDIM + t], 0.0f);
    if (blk == NBATCH && t < NBATCH)      atomicExch(&amax[t], 0ULL);
    grid.sync();

    const int b     = blk / BPB;
    const int chunk = blk % BPB;
    const float* xb = x + (size_t)b * NROW * CDIM;
    const int nbase = chunk * RPB + wave * RPW;

    // ---------------- phase 1: S[b] = sum over rows of u (normalized centered row)
    float a0 = 0.f, a1 = 0.f, a2 = 0.f, a3 = 0.f;
    for (int r = 0; r < RPW; ++r) {
        const float4 v = *reinterpret_cast<const float4*>(
            xb + (size_t)(nbase + r) * CDIM + lane * 4);
        float sa = v.x + v.y + v.z + v.w;
        float sb = v.x * v.x + v.y * v.y + v.z * v.z + v.w * v.w;
#pragma unroll
        for (int off = 1; off < 64; off <<= 1) {
            sa += __shfl_xor(sa, off, 64);
            sb += __shfl_xor(sb, off, 64);
        }
        const float mu  = sa * (1.0f / CDIM);
        const float inv = rsqrtf(sb - sa * mu);   // eps cancels in u
        a0 += (v.x - mu) * inv;
        a1 += (v.y - mu) * inv;
        a2 += (v.z - mu) * inv;
        a3 += (v.w - mu) * inv;
    }
    *reinterpret_cast<float4*>(&lds[wave][lane * 4]) = make_float4(a0, a1, a2, a3);
    __syncthreads();
    atomicAdd(&S[b * CDIM + t], lds[0][t] + lds[1][t] + lds[2][t] + lds[3][t]);
    grid.sync();

    // ---------------- phase 2: density = u . S ; per-batch argmax
    const float4 Sv = *reinterpret_cast<const float4*>(S + b * CDIM + lane * 4);
    float sumS = Sv.x + Sv.y + Sv.z + Sv.w;
#pragma unroll
    for (int off = 1; off < 64; off <<= 1) sumS += __shfl_xor(sumS, off, 64);

    float best  = -1e30f;
    int   bestn = 0;
    for (int r = 0; r < RPW; ++r) {
        const int n = nbase + r;
        const float4 v = *reinterpret_cast<const float4*>(
            xb + (size_t)n * CDIM + lane * 4);
        float sa = v.x + v.y + v.z + v.w;
        float sb = v.x * v.x + v.y * v.y + v.z * v.z + v.w * v.w;
        float sc = v.x * Sv.x + v.y * Sv.y + v.z * Sv.z + v.w * Sv.w;
#pragma unroll
        for (int off = 1; off < 64; off <<= 1) {
            sa += __shfl_xor(sa, off, 64);
            sb += __shfl_xor(sb, off, 64);
            sc += __shfl_xor(sc, off, 64);
        }
        const float mu   = sa * (1.0f / CDIM);
        const float ss   = sb - sa * mu;      // sum (v-mu)^2
        const float dotS = sc - mu * sumS;    // (v-mu) . S
        const float dens = dotS * rsqrtf(ss);
        if (dens > best) { best = dens; bestn = n; }
    }
    if (lane == 0) {
        unsigned key = __float_as_uint(best);
        key = (key & 0x80000000u) ? ~key : (key | 0x80000000u);  // order-preserving
        wbest[wave] = ((unsigned long long)key << 32) | (unsigned)bestn;
    }
    __syncthreads();
    if (t == 0) {
        unsigned long long m = wbest[0];
#pragma unroll
        for (int w = 1; w < 4; ++w) m = m > wbest[w] ? m : wbest[w];
        atomicMax(&amax[b], m);
    }
    grid.sync();

    // ---------------- phase 3: LN(argmax row) -> proj -> relu (blocks 0..7)
    if (blk < NBATCH) {
        const int bb = blk;
        const int n  = (int)(amax[bb] & 0xFFFFFFFFULL);
        const float* row = x + ((size_t)bb * NROW + n) * CDIM;
        const float v = row[t];

        float s = v;
#pragma unroll
        for (int off = 1; off < 64; off <<= 1) s += __shfl_xor(s, off, 64);
        if (lane == 0) red[wave] = s;
        __syncthreads();
        const float mu = (red[0] + red[1] + red[2] + red[3]) * (1.0f / CDIM);

        const float d = v - mu;
        float s2 = d * d;
#pragma unroll
        for (int off = 1; off < 64; off <<= 1) s2 += __shfl_xor(s2, off, 64);
        if (lane == 0) red[4 + wave] = s2;
        __syncthreads();
        const float var = (red[4] + red[5] + red[6] + red[7]) * (1.0f / CDIM);
        const float rs  = rsqrtf(var + 1e-5f);

        y[t] = d * rs * lnw[t] + lnb[t];
        __syncthreads();

        const int dcol = t >> 2;
        const int part = t & 3;
        const float* wrow = pw + dcol * CDIM + part * 64;
        const float* yp   = y + part * 64;
        float p = 0.f;
#pragma unroll
        for (int c = 0; c < 64; ++c) p += yp[c] * wrow[c];
        p += __shfl_xor(p, 1, 64);
        p += __shfl_xor(p, 2, 64);
        if (part == 0) out[bb * CR + dcol] = fmaxf(p + pb[dcol], 0.0f);
    }
}

// ------------------------------------------------------------------ launch ----
extern "C" void kernel_launch(void* const* d_in, const int* in_sizes, int n_in,
                              void* d_out, int out_size, void* d_ws, size_t ws_size,
                              hipStream_t stream) {
    const float* x   = (const float*)d_in[0];
    const float* lnw = (const float*)d_in[1];
    const float* lnb = (const float*)d_in[2];
    const float* pw  = (const float*)d_in[3];
    const float* pb  = (const float*)d_in[4];
    float* out = (float*)d_out;

    float* S = (float*)d_ws;                                             // 8*256 f32
    unsigned long long* amax =
        (unsigned long long*)((char*)d_ws + NBATCH * CDIM * sizeof(float)); // 8*u64

    void* args[] = {
        (void*)&x, (void*)&lnw, (void*)&lnb, (void*)&pw, (void*)&pb,
        (void*)&S, (void*)&amax, (void*)&out
    };
    hipLaunchCooperativeKernel((const void*)k_fused, dim3(GRID), dim3(256),
                               args, 0, stream);
}